// Round 3
// baseline (957.407 us; speedup 1.0000x reference)
//
#include <hip/hip_runtime.h>

#define B 64
#define SIZE 2048
#define L 16
#define A 64
#define HID 256
#define R_N 65536
#define XCOLS (SIZE + L)

#define ST_ELEMS ((L + 1) * SIZE * B)

__device__ __forceinline__ float bflo(unsigned int u) {
    return __uint_as_float(u << 16);
}
__device__ __forceinline__ float bfhi(unsigned int u) {
    return __uint_as_float(u & 0xffff0000u);
}
__device__ __forceinline__ unsigned short f2bf(float f) {
    unsigned int u = __float_as_uint(f);
    unsigned int r = (u + 0x7fffu + ((u >> 16) & 1u)) >> 16;
    return (unsigned short)r;
}

// ---------- init: zero ST[1..16], ST[0] = x^T, zero hist/cursor ----------
__global__ __launch_bounds__(256) void k_init(const int* __restrict__ x,
                                              float* __restrict__ ST,
                                              int* __restrict__ hist,
                                              int* __restrict__ cursor) {
    int tid = threadIdx.x;
    // all blocks: grid-stride zero of ST[1..16] (2M floats)
    float4* z = (float4*)(ST + (size_t)SIZE * B);
    int total4 = L * SIZE * B / 4;
    float4 zv = {0.f, 0.f, 0.f, 0.f};
    for (int i = blockIdx.x * 256 + tid; i < total4; i += gridDim.x * 256)
        z[i] = zv;
    if (blockIdx.x == 32) {
        for (int i = tid; i < 2048; i += 256) {
            hist[i] = 0;
            cursor[i] = 0;
        }
    }
    if (blockIdx.x < 32) {
        __shared__ float tile[64][65];
        int s0 = blockIdx.x * 64;
        for (int i = tid; i < 4096; i += 256) {
            int b = i >> 6, sc = i & 63;
            tile[b][sc] = (float)x[b * XCOLS + s0 + sc];
        }
        __syncthreads();
        for (int i = tid; i < 4096; i += 256) {
            int si = i >> 6, b = i & 63;
            ST[(size_t)(s0 + si) * B + b] = tile[b][si];
        }
    }
}

// ---------- histogram of rel_obj ----------
__global__ __launch_bounds__(256) void k_hist(const int* __restrict__ rel_obj,
                                              int* __restrict__ hist) {
    for (int i = blockIdx.x * 256 + threadIdx.x; i < R_N; i += 64 * 256)
        atomicAdd(&hist[rel_obj[i]], 1);
}

// ---------- exclusive scan (2048 bins), single block ----------
__global__ __launch_bounds__(256) void k_scan(const int* __restrict__ hist,
                                              int* __restrict__ off) {
    __shared__ int tsum[256];
    int tid = threadIdx.x;
    int v[8], pre[8];
    int s = 0;
#pragma unroll
    for (int i = 0; i < 8; i++) {
        v[i] = hist[tid * 8 + i];
        pre[i] = s;
        s += v[i];
    }
    tsum[tid] = s;
    __syncthreads();
    for (int ofs = 1; ofs < 256; ofs <<= 1) {
        int t = 0;
        if (tid >= ofs) t = tsum[tid - ofs];
        __syncthreads();
        tsum[tid] += t;
        __syncthreads();
    }
    int ebase = tsum[tid] - s;
#pragma unroll
    for (int i = 0; i < 8; i++) off[tid * 8 + i] = ebase + pre[i];
    if (tid == 255) off[2048] = tsum[255];
}

// ---------- scatter sorted positions ----------
__global__ __launch_bounds__(256) void k_scatter(const int* __restrict__ rel_subj,
                                                 const int* __restrict__ rel_obj,
                                                 const int* __restrict__ off,
                                                 int* __restrict__ cursor,
                                                 int* __restrict__ subjS,
                                                 int* __restrict__ objS) {
    for (int r = blockIdx.x * 256 + threadIdx.x; r < R_N; r += 64 * 256) {
        int obj = rel_obj[r];
        int pos = off[obj] + atomicAdd(&cursor[obj], 1);
        subjS[pos] = rel_subj[r];
        objS[pos] = obj;
    }
}

// ---------- P1 = emb @ W1a, P2 = emb @ W1b ----------
__global__ __launch_bounds__(256) void k_p12(const float* __restrict__ state_emb,
                                             const float* __restrict__ w1,
                                             float* __restrict__ P1,
                                             float* __restrict__ P2) {
    __shared__ float emb8[8][64];
    int tid = threadIdx.x;
    int sbase = blockIdx.x * 8;
    for (int i = tid; i < 512; i += 256)
        emb8[i >> 6][i & 63] = state_emb[(size_t)(sbase + (i >> 6)) * 64 + (i & 63)];
    __syncthreads();
    float acc1[8], acc2[8];
#pragma unroll
    for (int s = 0; s < 8; s++) { acc1[s] = 0.f; acc2[s] = 0.f; }
    for (int k = 0; k < 64; k++) {
        float wa = w1[(size_t)k * HID + tid];
        float wb = w1[(size_t)(64 + k) * HID + tid];
#pragma unroll
        for (int s = 0; s < 8; s++) {
            acc1[s] += emb8[s][k] * wa;
            acc2[s] += emb8[s][k] * wb;
        }
    }
#pragma unroll
    for (int s = 0; s < 8; s++) {
        P1[(size_t)(sbase + s) * HID + tid] = acc1[s];
        P2[(size_t)(sbase + s) * HID + tid] = acc2[s];
    }
}

// ---------- relS[i] = bf16( relu(P1[subj]+P2[obj]+b1) @ w2 + b2 ), sorted order ----------
__global__ __launch_bounds__(256) void k_rel2(const int* __restrict__ subjS,
                                              const int* __restrict__ objS,
                                              const float* __restrict__ P1,
                                              const float* __restrict__ P2,
                                              const float* __restrict__ b1,
                                              const float* __restrict__ w2,
                                              const float* __restrict__ b2,
                                              unsigned short* __restrict__ relS) {
    __shared__ unsigned short h4[64 * HID];  // bf16 hidden, 32 KB
    __shared__ int subj_l[64], obj_l[64];
    int tid = threadIdx.x;
    int rbase = blockIdx.x * 64;
    if (tid < 64) {
        subj_l[tid] = subjS[rbase + tid];
        obj_l[tid] = objS[rbase + tid];
    }
    __syncthreads();
    for (int e = tid; e < 64 * 64; e += 256) {
        int r = e >> 6, jc = e & 63;
        const float4 p1 = *(const float4*)&P1[(size_t)subj_l[r] * HID + jc * 4];
        const float4 p2 = *(const float4*)&P2[(size_t)obj_l[r] * HID + jc * 4];
        const float4 bv = *(const float4*)&b1[jc * 4];
        ushort4 hv;
        hv.x = f2bf(fmaxf(p1.x + p2.x + bv.x, 0.f));
        hv.y = f2bf(fmaxf(p1.y + p2.y + bv.y, 0.f));
        hv.z = f2bf(fmaxf(p1.z + p2.z + bv.z, 0.f));
        hv.w = f2bf(fmaxf(p1.w + p2.w + bv.w, 0.f));
        ((ushort4*)h4)[r * 64 + jc] = hv;
    }
    __syncthreads();
    int c = tid & 63, rg = tid >> 6;
    float acc[16];
#pragma unroll
    for (int r = 0; r < 16; r++) acc[r] = 0.f;
    for (int j4 = 0; j4 < 64; j4++) {
        float w0 = w2[(size_t)(j4 * 4 + 0) * 64 + c];
        float w1v = w2[(size_t)(j4 * 4 + 1) * 64 + c];
        float w2v = w2[(size_t)(j4 * 4 + 2) * 64 + c];
        float w3 = w2[(size_t)(j4 * 4 + 3) * 64 + c];
#pragma unroll
        for (int r = 0; r < 16; r++) {
            ushort4 hv = ((ushort4*)h4)[(rg * 16 + r) * 64 + j4];
            acc[r] += bflo(hv.x) * w0 + bflo(hv.y) * w1v + bflo(hv.z) * w2v +
                      bflo(hv.w) * w3;
        }
    }
    float b2v = b2[c];
#pragma unroll
    for (int r = 0; r < 16; r++)
        relS[(size_t)(rbase + rg * 16 + r) * 64 + c] = f2bf(acc[r] + b2v);
}

// ---------- meta chain: folded algebra, weights in registers (no spill!) ----------
__global__ __launch_bounds__(256, 1) void k_meta(
    const int* __restrict__ x, const float* __restrict__ action_emb,
    const float* __restrict__ pos_emb, const float* __restrict__ q_w,
    const float* __restrict__ q_b, const float* __restrict__ ms_w1,
    const float* __restrict__ ms_b1, const float* __restrict__ ms_w2,
    const float* __restrict__ ms_b2, const float* __restrict__ meta_init,
    float* __restrict__ metas) {
    __shared__ float sent[L][128];
    __shared__ float meta_lds[A];
    __shared__ float logits_lds[L];
    __shared__ float qb_lds[L];
    __shared__ float hidden_lds[HID];
    __shared__ float parts[4][A];
    __shared__ float b2_lds[A];
    int tid = threadIdx.x;
    int b = blockIdx.x;

    for (int i = tid; i < L * 128; i += 256) {
        int l = i >> 7, d = i & 127;
        float v;
        if (d < 64) {
            int act = x[b * XCOLS + SIZE + l];
            v = action_emb[act * 64 + d];
        } else {
            v = pos_emb[l * 64 + (d - 64)];
        }
        sent[l][d] = v;
    }
    if (tid < A) {
        meta_lds[tid] = meta_init[tid];
        b2_lds[tid] = ms_b2[tid];
    }
    __syncthreads();

    float w1a_r[64];
#pragma unroll
    for (int k = 0; k < 64; k++) w1a_r[k] = ms_w1[(size_t)k * HID + tid];
    float sentw_r[16];
#pragma unroll
    for (int l = 0; l < 16; l++) sentw_r[l] = 0.f;
    for (int d = 0; d < 128; d++) {
        float w = ms_w1[(size_t)(64 + d) * HID + tid];
#pragma unroll
        for (int l = 0; l < 16; l++) sentw_r[l] += sent[l][d] * w;
    }
    int c = tid & 63, kg = tid >> 6;
    float w2_r[64];
#pragma unroll
    for (int i = 0; i < 64; i++) w2_r[i] = ms_w2[(size_t)(kg * 64 + i) * 64 + c];
    int l_q = tid >> 4, sub = tid & 15;
    float qs_r[4];
#pragma unroll
    for (int i = 0; i < 4; i++) {
        int k = sub * 4 + i;
        float a = 0.f;
#pragma unroll 8
        for (int j = 0; j < 128; j++) a += q_w[(size_t)k * 128 + j] * sent[l_q][j];
        qs_r[i] = a;
    }
    if (tid < 16) {
        float a = 0.f;
        for (int j = 0; j < 128; j++) a += q_b[j] * sent[tid][j];
        qb_lds[tid] = a;
    }
    float b1r = ms_b1[tid];
    __syncthreads();

    for (int t = 0; t < L; t++) {
        float p = 0.f;
#pragma unroll
        for (int i = 0; i < 4; i++) p += meta_lds[sub * 4 + i] * qs_r[i];
        p += __shfl_xor(p, 8);
        p += __shfl_xor(p, 4);
        p += __shfl_xor(p, 2);
        p += __shfl_xor(p, 1);
        if (sub == 0) logits_lds[l_q] = p + qb_lds[l_q];
        __syncthreads();
        float mx = logits_lds[0];
#pragma unroll
        for (int l = 1; l < 16; l++) mx = fmaxf(mx, logits_lds[l]);
        float attn[16];
        float se = 0.f;
#pragma unroll
        for (int l = 0; l < 16; l++) {
            attn[l] = __expf(logits_lds[l] - mx);
            se += attn[l];
        }
        float inv = 1.f / se;
        float h = b1r;
#pragma unroll
        for (int k = 0; k < 64; k++) h += meta_lds[k] * w1a_r[k];
#pragma unroll
        for (int l = 0; l < 16; l++) h += attn[l] * inv * sentw_r[l];
        hidden_lds[tid] = fmaxf(h, 0.f);
        __syncthreads();
        float pp = 0.f;
#pragma unroll
        for (int i = 0; i < 64; i++) pp += hidden_lds[kg * 64 + i] * w2_r[i];
        parts[kg][c] = pp;
        __syncthreads();
        if (tid < A) {
            float nm = b2_lds[tid] + parts[0][tid] + parts[1][tid] +
                       parts[2][tid] + parts[3][tid];
            meta_lds[tid] = nm;
            metas[((size_t)t * B + b) * A + tid] = nm;
        }
        __syncthreads();
    }
}

// ---------- flush helper for k_step ----------
__device__ __forceinline__ void flush_seg(float* __restrict__ st_out, int obj,
                                          float acc, int lane,
                                          const int* __restrict__ off, int base) {
    int s = off[obj], e = off[obj + 1];
    if (s >= base && e <= base + 16)
        st_out[(size_t)obj * B + lane] = acc;
    else
        atomicAdd(&st_out[(size_t)obj * B + lane], acc);
}

// ---------- state step: balanced (16 sorted relations per wave) ----------
__global__ __launch_bounds__(256) void k_step(const int* __restrict__ off,
                                              const int* __restrict__ subjS,
                                              const int* __restrict__ objS,
                                              const unsigned short* __restrict__ relS,
                                              const float* __restrict__ metas,
                                              const float* __restrict__ st_in,
                                              float* __restrict__ st_out, int t) {
    int tid = threadIdx.x;
    int lane = tid & 63;
    int gw = blockIdx.x * 4 + (tid >> 6);  // 0..4095
    int base = gw * 16;

    float4 m[16];
    const float4* mp = (const float4*)(metas + ((size_t)t * B + lane) * A);
#pragma unroll
    for (int i = 0; i < 16; i++) m[i] = mp[i];

    float acc = 0.f;
    int cur_obj = objS[base];

#pragma unroll 1
    for (int ch = 0; ch < 2; ch++) {
        int b0 = base + ch * 8;
        float vals[8];
        int ob[8];
#pragma unroll
        for (int i = 0; i < 8; i++) {
            int r = b0 + i;
            int subj = subjS[r];
            ob[i] = objS[r];
            const uint4* rp = (const uint4*)(relS + (size_t)r * 64);
            float4 s0 = {0.f, 0.f, 0.f, 0.f}, s1 = {0.f, 0.f, 0.f, 0.f};
#pragma unroll
            for (int q = 0; q < 8; q++) {
                uint4 u = rp[q];
                float4 m0 = m[2 * q], m1 = m[2 * q + 1];
                s0.x += m0.x * bflo(u.x);
                s0.y += m0.y * bfhi(u.x);
                s0.z += m0.z * bflo(u.y);
                s0.w += m0.w * bfhi(u.y);
                s1.x += m1.x * bflo(u.z);
                s1.y += m1.y * bfhi(u.z);
                s1.z += m1.z * bflo(u.w);
                s1.w += m1.w * bfhi(u.w);
            }
            float dot = (s0.x + s0.y + s0.z + s0.w) + (s1.x + s1.y + s1.z + s1.w);
            float hs = 1.f / (1.f + __expf(-dot));
            vals[i] = st_in[(size_t)subj * B + lane] * hs;
        }
#pragma unroll
        for (int i = 0; i < 8; i++) {
            if (ob[i] != cur_obj) {
                flush_seg(st_out, cur_obj, acc, lane, off, base);
                acc = 0.f;
                cur_obj = ob[i];
            }
            acc += vals[i];
        }
    }
    flush_seg(st_out, cur_obj, acc, lane, off, base);
}

// ---------- final transpose ----------
__global__ __launch_bounds__(256) void k_out(const float* __restrict__ ST,
                                             float* __restrict__ out) {
    __shared__ float tile[64][65];
    int t = blockIdx.x >> 5;
    int s0 = (blockIdx.x & 31) * 64;
    const float* src = ST + (size_t)(t + 1) * SIZE * B;
    int tid = threadIdx.x;
    for (int i = tid; i < 64 * 64; i += 256) {
        int si = i >> 6, b = i & 63;
        tile[si][b] = src[(size_t)(s0 + si) * B + b];
    }
    __syncthreads();
    for (int i = tid; i < 64 * 64; i += 256) {
        int b = i >> 6, si = i & 63;
        out[((size_t)b * L + t) * SIZE + s0 + si] = tile[si][b];
    }
}

extern "C" void kernel_launch(void* const* d_in, const int* in_sizes, int n_in,
                              void* d_out, int out_size, void* d_ws,
                              size_t ws_size, hipStream_t stream) {
    const int* x = (const int*)d_in[0];
    const int* rel_subj = (const int*)d_in[1];
    const int* rel_obj = (const int*)d_in[2];
    const float* action_emb = (const float*)d_in[3];
    const float* pos_emb = (const float*)d_in[4];
    const float* state_emb = (const float*)d_in[5];
    const float* s2r_w1 = (const float*)d_in[6];
    const float* s2r_b1 = (const float*)d_in[7];
    const float* s2r_w2 = (const float*)d_in[8];
    const float* s2r_b2 = (const float*)d_in[9];
    const float* q_w = (const float*)d_in[10];
    const float* q_b = (const float*)d_in[11];
    const float* ms_w1 = (const float*)d_in[12];
    const float* ms_b1 = (const float*)d_in[13];
    const float* ms_w2 = (const float*)d_in[14];
    const float* ms_b2 = (const float*)d_in[15];
    const float* meta_init = (const float*)d_in[16];

    float* ws = (float*)d_ws;
    float* ST = ws;
    unsigned short* relS = (unsigned short*)(ws + ST_ELEMS);
    float* metas = ws + ST_ELEMS + R_N * 64 / 2;
    float* P1 = metas + L * B * A;
    float* P2 = P1 + SIZE * HID;
    int* ibase = (int*)(P2 + SIZE * HID);
    int* hist = ibase;
    int* off = ibase + 2048;
    int* cursor = off + 2049;
    int* subjS = cursor + 2048;
    int* objS = subjS + R_N;
    float* out = (float*)d_out;

    k_init<<<256, 256, 0, stream>>>(x, ST, hist, cursor);
    k_hist<<<64, 256, 0, stream>>>(rel_obj, hist);
    k_scan<<<1, 256, 0, stream>>>(hist, off);
    k_scatter<<<64, 256, 0, stream>>>(rel_subj, rel_obj, off, cursor, subjS, objS);
    k_p12<<<SIZE / 8, 256, 0, stream>>>(state_emb, s2r_w1, P1, P2);
    k_rel2<<<R_N / 64, 256, 0, stream>>>(subjS, objS, P1, P2, s2r_b1, s2r_w2,
                                         s2r_b2, relS);
    k_meta<<<B, 256, 0, stream>>>(x, action_emb, pos_emb, q_w, q_b, ms_w1,
                                  ms_b1, ms_w2, ms_b2, meta_init, metas);
    for (int t = 0; t < L; t++) {
        k_step<<<1024, 256, 0, stream>>>(off, subjS, objS, relS, metas,
                                         ST + (size_t)t * SIZE * B,
                                         ST + (size_t)(t + 1) * SIZE * B, t);
    }
    k_out<<<512, 256, 0, stream>>>(ST, out);
}

// Round 4
// 449.250 us; speedup vs baseline: 2.1311x; 2.1311x over previous
//
#include <hip/hip_runtime.h>

#define B 64
#define SIZE 2048
#define L 16
#define A 64
#define HID 256
#define R_N 65536
#define XCOLS (SIZE + L)
#define ST_ELEMS ((L + 1) * SIZE * B)
#define RPB 128

typedef short bf16x8 __attribute__((ext_vector_type(8)));
typedef float f32x4 __attribute__((ext_vector_type(4)));

__device__ __forceinline__ float bflo(unsigned int u) {
    return __uint_as_float(u << 16);
}
__device__ __forceinline__ float bfhi(unsigned int u) {
    return __uint_as_float(u & 0xffff0000u);
}
__device__ __forceinline__ unsigned short f2bf(float f) {
    unsigned int u = __float_as_uint(f);
    unsigned int r = (u + 0x7fffu + ((u >> 16) & 1u)) >> 16;
    return (unsigned short)r;
}

// ---------- init: zero ST[1..16], ST[0] = x^T, zero hist/cursor ----------
__global__ __launch_bounds__(256) void k_init(const int* __restrict__ x,
                                              float* __restrict__ ST,
                                              int* __restrict__ hist,
                                              int* __restrict__ cursor) {
    int tid = threadIdx.x;
    float4* z = (float4*)(ST + (size_t)SIZE * B);
    int total4 = L * SIZE * B / 4;
    float4 zv = {0.f, 0.f, 0.f, 0.f};
    for (int i = blockIdx.x * 256 + tid; i < total4; i += gridDim.x * 256)
        z[i] = zv;
    if (blockIdx.x == 32) {
        for (int i = tid; i < 2048; i += 256) {
            hist[i] = 0;
            cursor[i] = 0;
        }
    }
    if (blockIdx.x < 32) {
        __shared__ float tile[64][65];
        int s0 = blockIdx.x * 64;
        for (int i = tid; i < 4096; i += 256) {
            int b = i >> 6, sc = i & 63;
            tile[b][sc] = (float)x[b * XCOLS + s0 + sc];
        }
        __syncthreads();
        for (int i = tid; i < 4096; i += 256) {
            int si = i >> 6, b = i & 63;
            ST[(size_t)(s0 + si) * B + b] = tile[b][si];
        }
    }
}

// ---------- histogram of rel_obj ----------
__global__ __launch_bounds__(256) void k_hist(const int* __restrict__ rel_obj,
                                              int* __restrict__ hist) {
    for (int i = blockIdx.x * 256 + threadIdx.x; i < R_N; i += 64 * 256)
        atomicAdd(&hist[rel_obj[i]], 1);
}

// ---------- exclusive scan (2048 bins), single block ----------
__global__ __launch_bounds__(256) void k_scan(const int* __restrict__ hist,
                                              int* __restrict__ off) {
    __shared__ int tsum[256];
    int tid = threadIdx.x;
    int v[8], pre[8];
    int s = 0;
#pragma unroll
    for (int i = 0; i < 8; i++) {
        v[i] = hist[tid * 8 + i];
        pre[i] = s;
        s += v[i];
    }
    tsum[tid] = s;
    __syncthreads();
    for (int ofs = 1; ofs < 256; ofs <<= 1) {
        int t = 0;
        if (tid >= ofs) t = tsum[tid - ofs];
        __syncthreads();
        tsum[tid] += t;
        __syncthreads();
    }
    int ebase = tsum[tid] - s;
#pragma unroll
    for (int i = 0; i < 8; i++) off[tid * 8 + i] = ebase + pre[i];
    if (tid == 255) off[2048] = tsum[255];
}

// ---------- scatter sorted positions ----------
__global__ __launch_bounds__(256) void k_scatter(const int* __restrict__ rel_subj,
                                                 const int* __restrict__ rel_obj,
                                                 const int* __restrict__ off,
                                                 int* __restrict__ cursor,
                                                 int* __restrict__ subjS,
                                                 int* __restrict__ objS) {
    for (int r = blockIdx.x * 256 + threadIdx.x; r < R_N; r += 64 * 256) {
        int obj = rel_obj[r];
        int pos = off[obj] + atomicAdd(&cursor[obj], 1);
        subjS[pos] = rel_subj[r];
        objS[pos] = obj;
    }
}

// ---------- P1 = emb @ W1a, P2 = emb @ W1b ----------
__global__ __launch_bounds__(256) void k_p12(const float* __restrict__ state_emb,
                                             const float* __restrict__ w1,
                                             float* __restrict__ P1,
                                             float* __restrict__ P2) {
    __shared__ float emb8[8][64];
    int tid = threadIdx.x;
    int sbase = blockIdx.x * 8;
    for (int i = tid; i < 512; i += 256)
        emb8[i >> 6][i & 63] = state_emb[(size_t)(sbase + (i >> 6)) * 64 + (i & 63)];
    __syncthreads();
    float acc1[8], acc2[8];
#pragma unroll
    for (int s = 0; s < 8; s++) { acc1[s] = 0.f; acc2[s] = 0.f; }
    for (int k = 0; k < 64; k++) {
        float wa = w1[(size_t)k * HID + tid];
        float wb = w1[(size_t)(64 + k) * HID + tid];
#pragma unroll
        for (int s = 0; s < 8; s++) {
            acc1[s] += emb8[s][k] * wa;
            acc2[s] += emb8[s][k] * wb;
        }
    }
#pragma unroll
    for (int s = 0; s < 8; s++) {
        P1[(size_t)(sbase + s) * HID + tid] = acc1[s];
        P2[(size_t)(sbase + s) * HID + tid] = acc2[s];
    }
}

// ---------- relS[i] = bf16( relu(P1[subj]+P2[obj]+b1) @ w2 + b2 ), sorted order ----------
__global__ __launch_bounds__(256) void k_rel2(const int* __restrict__ subjS,
                                              const int* __restrict__ objS,
                                              const float* __restrict__ P1,
                                              const float* __restrict__ P2,
                                              const float* __restrict__ b1,
                                              const float* __restrict__ w2,
                                              const float* __restrict__ b2,
                                              unsigned short* __restrict__ relS) {
    __shared__ unsigned short h4[64 * HID];
    __shared__ int subj_l[64], obj_l[64];
    int tid = threadIdx.x;
    int rbase = blockIdx.x * 64;
    if (tid < 64) {
        subj_l[tid] = subjS[rbase + tid];
        obj_l[tid] = objS[rbase + tid];
    }
    __syncthreads();
    for (int e = tid; e < 64 * 64; e += 256) {
        int r = e >> 6, jc = e & 63;
        const float4 p1 = *(const float4*)&P1[(size_t)subj_l[r] * HID + jc * 4];
        const float4 p2 = *(const float4*)&P2[(size_t)obj_l[r] * HID + jc * 4];
        const float4 bv = *(const float4*)&b1[jc * 4];
        ushort4 hv;
        hv.x = f2bf(fmaxf(p1.x + p2.x + bv.x, 0.f));
        hv.y = f2bf(fmaxf(p1.y + p2.y + bv.y, 0.f));
        hv.z = f2bf(fmaxf(p1.z + p2.z + bv.z, 0.f));
        hv.w = f2bf(fmaxf(p1.w + p2.w + bv.w, 0.f));
        ((ushort4*)h4)[r * 64 + jc] = hv;
    }
    __syncthreads();
    int c = tid & 63, rg = tid >> 6;
    float acc[16];
#pragma unroll
    for (int r = 0; r < 16; r++) acc[r] = 0.f;
    for (int j4 = 0; j4 < 64; j4++) {
        float w0 = w2[(size_t)(j4 * 4 + 0) * 64 + c];
        float w1v = w2[(size_t)(j4 * 4 + 1) * 64 + c];
        float w2v = w2[(size_t)(j4 * 4 + 2) * 64 + c];
        float w3 = w2[(size_t)(j4 * 4 + 3) * 64 + c];
#pragma unroll
        for (int r = 0; r < 16; r++) {
            ushort4 hv = ((ushort4*)h4)[(rg * 16 + r) * 64 + j4];
            acc[r] += bflo(hv.x) * w0 + bflo(hv.y) * w1v + bflo(hv.z) * w2v +
                      bflo(hv.w) * w3;
        }
    }
    float b2v = b2[c];
#pragma unroll
    for (int r = 0; r < 16; r++)
        relS[(size_t)(rbase + rg * 16 + r) * 64 + c] = f2bf(acc[r] + b2v);
}

// ---------- meta chain: 1024 threads, small reg arrays, no spill ----------
__global__ __launch_bounds__(1024) void k_meta(
    const int* __restrict__ x, const float* __restrict__ action_emb,
    const float* __restrict__ pos_emb, const float* __restrict__ q_w,
    const float* __restrict__ q_b, const float* __restrict__ ms_w1,
    const float* __restrict__ ms_b1, const float* __restrict__ ms_w2,
    const float* __restrict__ ms_b2, const float* __restrict__ meta_init,
    unsigned short* __restrict__ metas_bf) {
    __shared__ float sent[L][132];     // padded: kills 16-way conflicts
    __shared__ float qs[A][17];        // qs[k][l], padded
    __shared__ float qb_lds[L];
    __shared__ float meta_lds[A];
    __shared__ float logits_lds[L];
    __shared__ float attn_lds[L];
    __shared__ float hidden_lds[HID];
    __shared__ float parts[16][65];
    __shared__ float b2_lds[A];
    int tid = threadIdx.x;
    int b = blockIdx.x;
    int lane = tid & 63, wv = tid >> 6;

    for (int i = tid; i < L * 128; i += 1024) {
        int l = i >> 7, d = i & 127;
        float v;
        if (d < 64)
            v = action_emb[x[b * XCOLS + SIZE + l] * 64 + d];
        else
            v = pos_emb[l * 64 + (d - 64)];
        sent[l][d] = v;
    }
    if (tid < A) {
        meta_lds[tid] = meta_init[tid];
        b2_lds[tid] = ms_b2[tid];
    }
    __syncthreads();

    // qs[k][l] = sum_j q_w[k][j] * sent[l][j]  (one entry per thread)
    {
        int k = tid >> 4, l = tid & 15;
        float a = 0.f;
        for (int j = 0; j < 128; j++) a += q_w[(size_t)k * 128 + j] * sent[l][j];
        qs[k][l] = a;
    }
    if (tid < L) {
        float a = 0.f;
        for (int j = 0; j < 128; j++) a += q_b[j] * sent[tid][j];
        qb_lds[tid] = a;
    }
    // hidden phase identity: 4 threads per hidden unit j
    int j_h = tid >> 2, q_h = tid & 3;
    float w1a_r[16];
#pragma unroll
    for (int i = 0; i < 16; i++)
        w1a_r[i] = ms_w1[(size_t)(q_h * 16 + i) * HID + j_h];
    float sentw_r[4];
#pragma unroll
    for (int i = 0; i < 4; i++) sentw_r[i] = 0.f;
    for (int d = 0; d < 128; d++) {
        float w = ms_w1[(size_t)(64 + d) * HID + j_h];
#pragma unroll
        for (int i = 0; i < 4; i++) sentw_r[i] += sent[q_h * 4 + i][d] * w;
    }
    float b1_r = ms_b1[j_h];
    // meta2 identity: wave g handles k-chunk, lane = out col
    int g_m = tid >> 6, c_m = tid & 63;
    float w2_r[16];
#pragma unroll
    for (int i = 0; i < 16; i++)
        w2_r[i] = ms_w2[(size_t)(g_m * 16 + i) * 64 + c_m];
    __syncthreads();

    for (int t = 0; t < L; t++) {
        // logits: wave wv owns l = wv; lane = k
        float p = meta_lds[lane] * qs[lane][wv];
        p += __shfl_xor(p, 32);
        p += __shfl_xor(p, 16);
        p += __shfl_xor(p, 8);
        p += __shfl_xor(p, 4);
        p += __shfl_xor(p, 2);
        p += __shfl_xor(p, 1);
        if (lane == 0) logits_lds[wv] = p + qb_lds[wv];
        __syncthreads();
        if (tid < L) {
            float mx = logits_lds[0];
#pragma unroll
            for (int l = 1; l < L; l++) mx = fmaxf(mx, logits_lds[l]);
            float sum = 0.f;
#pragma unroll
            for (int l = 0; l < L; l++) sum += __expf(logits_lds[l] - mx);
            attn_lds[tid] = __expf(logits_lds[tid] - mx) / sum;
        }
        __syncthreads();
        // hidden[j] = relu(b1 + meta@W1a[:,j] + attn@sentW[:,j]) via 4-way split
        float h = 0.f;
#pragma unroll
        for (int i = 0; i < 16; i++) h += meta_lds[q_h * 16 + i] * w1a_r[i];
#pragma unroll
        for (int i = 0; i < 4; i++) h += attn_lds[q_h * 4 + i] * sentw_r[i];
        h += __shfl_xor(h, 1);
        h += __shfl_xor(h, 2);
        if (q_h == 0) hidden_lds[j_h] = fmaxf(h + b1_r, 0.f);
        __syncthreads();
        // meta' split-k over 16 waves
        float pp = 0.f;
#pragma unroll
        for (int i = 0; i < 16; i++) pp += hidden_lds[g_m * 16 + i] * w2_r[i];
        parts[g_m][c_m] = pp;
        __syncthreads();
        if (tid < A) {
            float nm = b2_lds[tid];
#pragma unroll
            for (int g = 0; g < 16; g++) nm += parts[g][tid];
            meta_lds[tid] = nm;
            metas_bf[((size_t)t * B + b) * A + tid] = f2bf(nm);
        }
        __syncthreads();
    }
}

// ---------- state step: MFMA dot + sorted segmented flush ----------
// grid 512; block = 128 sorted relations; 4 waves
__global__ __launch_bounds__(256) void k_step(
    const int* __restrict__ off, const int* __restrict__ subjS,
    const int* __restrict__ objS, const unsigned short* __restrict__ relS,
    const unsigned short* __restrict__ mb,  // metas_bf + t*B*A, [b][k] bf16
    const float* __restrict__ st_in, float* __restrict__ st_out) {
    __shared__ float vals[RPB][66];  // pad 66 -> <=2-way bank alias (free)
    __shared__ int obj_l[RPB], subj_l[RPB];
    int tid = threadIdx.x, lane = tid & 63, w = tid >> 6;
    int rbase = blockIdx.x * RPB;
    int lr = lane & 15, lh = lane >> 4;

    if (tid < RPB) {
        obj_l[tid] = objS[rbase + tid];
        subj_l[tid] = subjS[rbase + tid];
    }

    // B fragments: metas (4 col-tiles x 2 K-halves)
    bf16x8 bfrag[4][2];
#pragma unroll
    for (int ct = 0; ct < 4; ct++)
#pragma unroll
        for (int kk = 0; kk < 2; kk++)
            bfrag[ct][kk] =
                *(const bf16x8*)(mb + (ct * 16 + lr) * 64 + kk * 32 + lh * 8);
    // A fragments: relS rows (2 row-tiles x 2 K-halves) per wave
    bf16x8 afrag[2][2];
#pragma unroll
    for (int rt = 0; rt < 2; rt++)
#pragma unroll
        for (int kk = 0; kk < 2; kk++)
            afrag[rt][kk] = *(const bf16x8*)(relS +
                (size_t)(rbase + w * 32 + rt * 16 + lr) * 64 + kk * 32 + lh * 8);

    f32x4 acc[2][4];
#pragma unroll
    for (int rt = 0; rt < 2; rt++)
#pragma unroll
        for (int ct = 0; ct < 4; ct++) {
            f32x4 c = {0.f, 0.f, 0.f, 0.f};
            c = __builtin_amdgcn_mfma_f32_16x16x32_bf16(afrag[rt][0],
                                                        bfrag[ct][0], c, 0, 0, 0);
            c = __builtin_amdgcn_mfma_f32_16x16x32_bf16(afrag[rt][1],
                                                        bfrag[ct][1], c, 0, 0, 0);
            acc[rt][ct] = c;
        }
    // sigmoid -> LDS  (C/D: col = lane&15, row = (lane>>4)*4 + reg)
#pragma unroll
    for (int rt = 0; rt < 2; rt++)
#pragma unroll
        for (int ct = 0; ct < 4; ct++)
#pragma unroll
            for (int rg = 0; rg < 4; rg++) {
                int r_loc = w * 32 + rt * 16 + lh * 4 + rg;
                int c = ct * 16 + lr;
                float d = acc[rt][ct][rg];
                vals[r_loc][c] = 1.f / (1.f + __expf(-d));
            }
    __syncthreads();

    // flush: wave w owns rows [32w, 32w+32)
    int base_w = rbase + w * 32;
    float acc_s = 0.f;
    int cur = obj_l[w * 32];
    for (int rr = 0; rr < 32; rr++) {
        int row = w * 32 + rr;
        int ob = obj_l[row];
        float sv = st_in[(size_t)subj_l[row] * B + lane];
        float v = vals[row][lane] * sv;
        if (ob != cur) {
            int s = off[cur], e = off[cur + 1];
            if (s >= base_w && e <= base_w + 32)
                st_out[(size_t)cur * B + lane] = acc_s;
            else
                atomicAdd(&st_out[(size_t)cur * B + lane], acc_s);
            acc_s = 0.f;
            cur = ob;
        }
        acc_s += v;
    }
    {
        int s = off[cur], e = off[cur + 1];
        if (s >= base_w && e <= base_w + 32)
            st_out[(size_t)cur * B + lane] = acc_s;
        else
            atomicAdd(&st_out[(size_t)cur * B + lane], acc_s);
    }
}

// ---------- final transpose ----------
__global__ __launch_bounds__(256) void k_out(const float* __restrict__ ST,
                                             float* __restrict__ out) {
    __shared__ float tile[64][65];
    int t = blockIdx.x >> 5;
    int s0 = (blockIdx.x & 31) * 64;
    const float* src = ST + (size_t)(t + 1) * SIZE * B;
    int tid = threadIdx.x;
    for (int i = tid; i < 64 * 64; i += 256) {
        int si = i >> 6, b = i & 63;
        tile[si][b] = src[(size_t)(s0 + si) * B + b];
    }
    __syncthreads();
    for (int i = tid; i < 64 * 64; i += 256) {
        int b = i >> 6, si = i & 63;
        out[((size_t)b * L + t) * SIZE + s0 + si] = tile[si][b];
    }
}

extern "C" void kernel_launch(void* const* d_in, const int* in_sizes, int n_in,
                              void* d_out, int out_size, void* d_ws,
                              size_t ws_size, hipStream_t stream) {
    const int* x = (const int*)d_in[0];
    const int* rel_subj = (const int*)d_in[1];
    const int* rel_obj = (const int*)d_in[2];
    const float* action_emb = (const float*)d_in[3];
    const float* pos_emb = (const float*)d_in[4];
    const float* state_emb = (const float*)d_in[5];
    const float* s2r_w1 = (const float*)d_in[6];
    const float* s2r_b1 = (const float*)d_in[7];
    const float* s2r_w2 = (const float*)d_in[8];
    const float* s2r_b2 = (const float*)d_in[9];
    const float* q_w = (const float*)d_in[10];
    const float* q_b = (const float*)d_in[11];
    const float* ms_w1 = (const float*)d_in[12];
    const float* ms_b1 = (const float*)d_in[13];
    const float* ms_w2 = (const float*)d_in[14];
    const float* ms_b2 = (const float*)d_in[15];
    const float* meta_init = (const float*)d_in[16];

    float* ws = (float*)d_ws;
    float* ST = ws;
    unsigned short* relS = (unsigned short*)(ws + ST_ELEMS);
    unsigned short* metas_bf = relS + (size_t)R_N * 64;
    float* P1 = (float*)(metas_bf + (size_t)L * B * A);
    float* P2 = P1 + SIZE * HID;
    int* ibase = (int*)(P2 + SIZE * HID);
    int* hist = ibase;
    int* off = ibase + 2048;
    int* cursor = off + 2049;
    int* subjS = cursor + 2048;
    int* objS = subjS + R_N;
    float* out = (float*)d_out;

    k_init<<<256, 256, 0, stream>>>(x, ST, hist, cursor);
    k_hist<<<64, 256, 0, stream>>>(rel_obj, hist);
    k_scan<<<1, 256, 0, stream>>>(hist, off);
    k_scatter<<<64, 256, 0, stream>>>(rel_subj, rel_obj, off, cursor, subjS, objS);
    k_p12<<<SIZE / 8, 256, 0, stream>>>(state_emb, s2r_w1, P1, P2);
    k_rel2<<<R_N / 64, 256, 0, stream>>>(subjS, objS, P1, P2, s2r_b1, s2r_w2,
                                         s2r_b2, relS);
    k_meta<<<B, 1024, 0, stream>>>(x, action_emb, pos_emb, q_w, q_b, ms_w1,
                                   ms_b1, ms_w2, ms_b2, meta_init, metas_bf);
    for (int t = 0; t < L; t++) {
        k_step<<<R_N / RPB, 256, 0, stream>>>(
            off, subjS, objS, relS, metas_bf + (size_t)t * B * A,
            ST + (size_t)t * SIZE * B, ST + (size_t)(t + 1) * SIZE * B);
    }
    k_out<<<512, 256, 0, stream>>>(ST, out);
}

// Round 5
// 339.347 us; speedup vs baseline: 2.8213x; 1.3239x over previous
//
#include <hip/hip_runtime.h>

#define B 64
#define SIZE 2048
#define L 16
#define A 64
#define HID 256
#define R_N 65536
#define XCOLS (SIZE + L)
#define ST_ELEMS ((L + 1) * SIZE * B)
#define RPB 128

typedef short bf16x8 __attribute__((ext_vector_type(8)));
typedef float f32x4 __attribute__((ext_vector_type(4)));

__device__ __forceinline__ unsigned short f2bf(float f) {
    unsigned int u = __float_as_uint(f);
    unsigned int r = (u + 0x7fffu + ((u >> 16) & 1u)) >> 16;
    return (unsigned short)r;
}

// ---------- init: zero ST[1..16], ST[0] = x^T, zero hist/cursor ----------
__global__ __launch_bounds__(256) void k_init(const int* __restrict__ x,
                                              float* __restrict__ ST,
                                              int* __restrict__ hist,
                                              int* __restrict__ cursor) {
    int tid = threadIdx.x;
    float4* z = (float4*)(ST + (size_t)SIZE * B);
    int total4 = L * SIZE * B / 4;
    float4 zv = {0.f, 0.f, 0.f, 0.f};
    for (int i = blockIdx.x * 256 + tid; i < total4; i += gridDim.x * 256)
        z[i] = zv;
    if (blockIdx.x == 32) {
        for (int i = tid; i < 2048; i += 256) {
            hist[i] = 0;
            cursor[i] = 0;
        }
    }
    if (blockIdx.x < 32) {
        __shared__ float tile[64][65];
        int s0 = blockIdx.x * 64;
        for (int i = tid; i < 4096; i += 256) {
            int b = i >> 6, sc = i & 63;
            tile[b][sc] = (float)x[b * XCOLS + s0 + sc];
        }
        __syncthreads();
        for (int i = tid; i < 4096; i += 256) {
            int si = i >> 6, b = i & 63;
            ST[(size_t)(s0 + si) * B + b] = tile[b][si];
        }
    }
}

// ---------- histogram of rel_obj ----------
__global__ __launch_bounds__(256) void k_hist(const int* __restrict__ rel_obj,
                                              int* __restrict__ hist) {
    for (int i = blockIdx.x * 256 + threadIdx.x; i < R_N; i += 64 * 256)
        atomicAdd(&hist[rel_obj[i]], 1);
}

// ---------- block 0: exclusive scan; block 1: w2t = bf16(w2^T) ----------
__global__ __launch_bounds__(256) void k_scan(const int* __restrict__ hist,
                                              int* __restrict__ off,
                                              const float* __restrict__ w2,
                                              unsigned short* __restrict__ w2t) {
    int tid = threadIdx.x;
    if (blockIdx.x == 1) {
        for (int i = tid; i < 64 * 256; i += 256) {
            int c = i >> 8, k = i & 255;
            w2t[i] = f2bf(w2[(size_t)k * 64 + c]);
        }
        return;
    }
    __shared__ int tsum[256];
    int v[8], pre[8];
    int s = 0;
#pragma unroll
    for (int i = 0; i < 8; i++) {
        v[i] = hist[tid * 8 + i];
        pre[i] = s;
        s += v[i];
    }
    tsum[tid] = s;
    __syncthreads();
    for (int ofs = 1; ofs < 256; ofs <<= 1) {
        int t = 0;
        if (tid >= ofs) t = tsum[tid - ofs];
        __syncthreads();
        tsum[tid] += t;
        __syncthreads();
    }
    int ebase = tsum[tid] - s;
#pragma unroll
    for (int i = 0; i < 8; i++) off[tid * 8 + i] = ebase + pre[i];
    if (tid == 255) off[2048] = tsum[255];
}

// ---------- scatter sorted positions ----------
__global__ __launch_bounds__(256) void k_scatter(const int* __restrict__ rel_subj,
                                                 const int* __restrict__ rel_obj,
                                                 const int* __restrict__ off,
                                                 int* __restrict__ cursor,
                                                 int* __restrict__ subjS,
                                                 int* __restrict__ objS) {
    for (int r = blockIdx.x * 256 + threadIdx.x; r < R_N; r += 64 * 256) {
        int obj = rel_obj[r];
        int pos = off[obj] + atomicAdd(&cursor[obj], 1);
        subjS[pos] = rel_subj[r];
        objS[pos] = obj;
    }
}

// ---------- P1 = emb @ W1a, P2 = emb @ W1b ----------
__global__ __launch_bounds__(256) void k_p12(const float* __restrict__ state_emb,
                                             const float* __restrict__ w1,
                                             float* __restrict__ P1,
                                             float* __restrict__ P2) {
    __shared__ float emb8[8][64];
    int tid = threadIdx.x;
    int sbase = blockIdx.x * 8;
    for (int i = tid; i < 512; i += 256)
        emb8[i >> 6][i & 63] = state_emb[(size_t)(sbase + (i >> 6)) * 64 + (i & 63)];
    __syncthreads();
    float acc1[8], acc2[8];
#pragma unroll
    for (int s = 0; s < 8; s++) { acc1[s] = 0.f; acc2[s] = 0.f; }
    for (int k = 0; k < 64; k++) {
        float wa = w1[(size_t)k * HID + tid];
        float wb = w1[(size_t)(64 + k) * HID + tid];
#pragma unroll
        for (int s = 0; s < 8; s++) {
            acc1[s] += emb8[s][k] * wa;
            acc2[s] += emb8[s][k] * wb;
        }
    }
#pragma unroll
    for (int s = 0; s < 8; s++) {
        P1[(size_t)(sbase + s) * HID + tid] = acc1[s];
        P2[(size_t)(sbase + s) * HID + tid] = acc2[s];
    }
}

// ---------- relS = bf16( relu(P1[subj]+P2[obj]+b1) @ w2 + b2 ) via MFMA ----------
// block = 128 sorted relations, 4 waves; grid 512
__global__ __launch_bounds__(256) void k_rel2(
    const int* __restrict__ subjS, const int* __restrict__ objS,
    const float* __restrict__ P1, const float* __restrict__ P2,
    const float* __restrict__ b1, const unsigned short* __restrict__ w2t,
    const float* __restrict__ b2, unsigned short* __restrict__ relS) {
    __shared__ unsigned short h[128][264];  // pad 264: <=2-way bank alias
    int tid = threadIdx.x, lane = tid & 63, w = tid >> 6;
    int rbase = blockIdx.x * 128;
    // stage hidden bf16 (per-wave row-uniform subj/obj, coalesced row reads)
    for (int e = tid; e < 128 * 64; e += 256) {
        int r = e >> 6, jc = (e & 63) * 4;
        int subj = subjS[rbase + r], obj = objS[rbase + r];
        float4 p1 = *(const float4*)&P1[(size_t)subj * HID + jc];
        float4 p2 = *(const float4*)&P2[(size_t)obj * HID + jc];
        float4 bv = *(const float4*)&b1[jc];
        ushort4 hv;
        hv.x = f2bf(fmaxf(p1.x + p2.x + bv.x, 0.f));
        hv.y = f2bf(fmaxf(p1.y + p2.y + bv.y, 0.f));
        hv.z = f2bf(fmaxf(p1.z + p2.z + bv.z, 0.f));
        hv.w = f2bf(fmaxf(p1.w + p2.w + bv.w, 0.f));
        *(ushort4*)&h[r][jc] = hv;
    }
    __syncthreads();
    int lr = lane & 15, lh = lane >> 4;
    f32x4 acc[2][4];
#pragma unroll
    for (int rt = 0; rt < 2; rt++)
#pragma unroll
        for (int ct = 0; ct < 4; ct++) acc[rt][ct] = (f32x4){0.f, 0.f, 0.f, 0.f};
#pragma unroll
    for (int kk = 0; kk < 8; kk++) {
        bf16x8 bfr[4], afr[2];
#pragma unroll
        for (int ct = 0; ct < 4; ct++)
            bfr[ct] = *(const bf16x8*)(w2t + (ct * 16 + lr) * 256 + kk * 32 + lh * 8);
#pragma unroll
        for (int rt = 0; rt < 2; rt++)
            afr[rt] = *(const bf16x8*)&h[w * 32 + rt * 16 + lr][kk * 32 + lh * 8];
#pragma unroll
        for (int rt = 0; rt < 2; rt++)
#pragma unroll
            for (int ct = 0; ct < 4; ct++)
                acc[rt][ct] = __builtin_amdgcn_mfma_f32_16x16x32_bf16(
                    afr[rt], bfr[ct], acc[rt][ct], 0, 0, 0);
    }
    float b2v[4];
#pragma unroll
    for (int ct = 0; ct < 4; ct++) b2v[ct] = b2[ct * 16 + lr];
#pragma unroll
    for (int rt = 0; rt < 2; rt++)
#pragma unroll
        for (int ct = 0; ct < 4; ct++)
#pragma unroll
            for (int rg = 0; rg < 4; rg++) {
                int row = rbase + w * 32 + rt * 16 + lh * 4 + rg;
                relS[(size_t)row * 64 + ct * 16 + lr] =
                    f2bf(acc[rt][ct][rg] + b2v[ct]);
            }
}

// ---------- meta chain: 1024 threads, small reg arrays ----------
__global__ __launch_bounds__(1024) void k_meta(
    const int* __restrict__ x, const float* __restrict__ action_emb,
    const float* __restrict__ pos_emb, const float* __restrict__ q_w,
    const float* __restrict__ q_b, const float* __restrict__ ms_w1,
    const float* __restrict__ ms_b1, const float* __restrict__ ms_w2,
    const float* __restrict__ ms_b2, const float* __restrict__ meta_init,
    unsigned short* __restrict__ metas_bf) {
    __shared__ float sent[L][132];
    __shared__ float qs[A][17];
    __shared__ float qb_lds[L];
    __shared__ float meta_lds[A];
    __shared__ float logits_lds[L];
    __shared__ float attn_lds[L];
    __shared__ float hidden_lds[HID];
    __shared__ float parts[16][65];
    __shared__ float b2_lds[A];
    int tid = threadIdx.x;
    int b = blockIdx.x;
    int lane = tid & 63, wv = tid >> 6;

    for (int i = tid; i < L * 128; i += 1024) {
        int l = i >> 7, d = i & 127;
        float v;
        if (d < 64)
            v = action_emb[x[b * XCOLS + SIZE + l] * 64 + d];
        else
            v = pos_emb[l * 64 + (d - 64)];
        sent[l][d] = v;
    }
    if (tid < A) {
        meta_lds[tid] = meta_init[tid];
        b2_lds[tid] = ms_b2[tid];
    }
    __syncthreads();

    {
        int k = tid >> 4, l = tid & 15;
        float a = 0.f;
        for (int j = 0; j < 128; j++) a += q_w[(size_t)k * 128 + j] * sent[l][j];
        qs[k][l] = a;
    }
    if (tid < L) {
        float a = 0.f;
        for (int j = 0; j < 128; j++) a += q_b[j] * sent[tid][j];
        qb_lds[tid] = a;
    }
    int j_h = tid >> 2, q_h = tid & 3;
    float w1a_r[16];
#pragma unroll
    for (int i = 0; i < 16; i++)
        w1a_r[i] = ms_w1[(size_t)(q_h * 16 + i) * HID + j_h];
    float sentw_r[4];
#pragma unroll
    for (int i = 0; i < 4; i++) sentw_r[i] = 0.f;
    for (int d = 0; d < 128; d++) {
        float w = ms_w1[(size_t)(64 + d) * HID + j_h];
#pragma unroll
        for (int i = 0; i < 4; i++) sentw_r[i] += sent[q_h * 4 + i][d] * w;
    }
    float b1_r = ms_b1[j_h];
    int g_m = tid >> 6, c_m = tid & 63;
    float w2_r[16];
#pragma unroll
    for (int i = 0; i < 16; i++)
        w2_r[i] = ms_w2[(size_t)(g_m * 16 + i) * 64 + c_m];
    __syncthreads();

    for (int t = 0; t < L; t++) {
        float p = meta_lds[lane] * qs[lane][wv];
        p += __shfl_xor(p, 32);
        p += __shfl_xor(p, 16);
        p += __shfl_xor(p, 8);
        p += __shfl_xor(p, 4);
        p += __shfl_xor(p, 2);
        p += __shfl_xor(p, 1);
        if (lane == 0) logits_lds[wv] = p + qb_lds[wv];
        __syncthreads();
        if (tid < L) {
            float mx = logits_lds[0];
#pragma unroll
            for (int l = 1; l < L; l++) mx = fmaxf(mx, logits_lds[l]);
            float sum = 0.f;
#pragma unroll
            for (int l = 0; l < L; l++) sum += __expf(logits_lds[l] - mx);
            attn_lds[tid] = __expf(logits_lds[tid] - mx) / sum;
        }
        __syncthreads();
        float h = 0.f;
#pragma unroll
        for (int i = 0; i < 16; i++) h += meta_lds[q_h * 16 + i] * w1a_r[i];
#pragma unroll
        for (int i = 0; i < 4; i++) h += attn_lds[q_h * 4 + i] * sentw_r[i];
        h += __shfl_xor(h, 1);
        h += __shfl_xor(h, 2);
        if (q_h == 0) hidden_lds[j_h] = fmaxf(h + b1_r, 0.f);
        __syncthreads();
        float pp = 0.f;
#pragma unroll
        for (int i = 0; i < 16; i++) pp += hidden_lds[g_m * 16 + i] * w2_r[i];
        parts[g_m][c_m] = pp;
        __syncthreads();
        if (tid < A) {
            float nm = b2_lds[tid];
#pragma unroll
            for (int g = 0; g < 16; g++) nm += parts[g][tid];
            meta_lds[tid] = nm;
            metas_bf[((size_t)t * B + b) * A + tid] = f2bf(nm);
        }
        __syncthreads();
    }
}

// ---------- state step: MFMA dot + register flush (sv/ob prefetched) ----------
__global__ __launch_bounds__(256) void k_step(
    const int* __restrict__ off, const int* __restrict__ subjS,
    const int* __restrict__ objS, const unsigned short* __restrict__ relS,
    const unsigned short* __restrict__ mb, const float* __restrict__ st_in,
    float* __restrict__ st_out) {
    __shared__ float vals[RPB][66];
    int tid = threadIdx.x, lane = tid & 63, w = tid >> 6;
    int rbase = blockIdx.x * RPB;
    int base_w = rbase + w * 32;
    int lr = lane & 15, lh = lane >> 4;

    // prefetch state gathers + obj ids (overlap with MFMA phase)
    float sv[32];
    int ob[32];
#pragma unroll
    for (int rr = 0; rr < 32; rr++) {
        sv[rr] = st_in[(size_t)subjS[base_w + rr] * B + lane];
        ob[rr] = objS[base_w + rr];
    }

    bf16x8 bfrag[4][2];
#pragma unroll
    for (int ct = 0; ct < 4; ct++)
#pragma unroll
        for (int kk = 0; kk < 2; kk++)
            bfrag[ct][kk] =
                *(const bf16x8*)(mb + (ct * 16 + lr) * 64 + kk * 32 + lh * 8);
    bf16x8 afrag[2][2];
#pragma unroll
    for (int rt = 0; rt < 2; rt++)
#pragma unroll
        for (int kk = 0; kk < 2; kk++)
            afrag[rt][kk] = *(const bf16x8*)(relS +
                (size_t)(rbase + w * 32 + rt * 16 + lr) * 64 + kk * 32 + lh * 8);

    f32x4 acc[2][4];
#pragma unroll
    for (int rt = 0; rt < 2; rt++)
#pragma unroll
        for (int ct = 0; ct < 4; ct++) {
            f32x4 c = {0.f, 0.f, 0.f, 0.f};
            c = __builtin_amdgcn_mfma_f32_16x16x32_bf16(afrag[rt][0],
                                                        bfrag[ct][0], c, 0, 0, 0);
            c = __builtin_amdgcn_mfma_f32_16x16x32_bf16(afrag[rt][1],
                                                        bfrag[ct][1], c, 0, 0, 0);
            acc[rt][ct] = c;
        }
#pragma unroll
    for (int rt = 0; rt < 2; rt++)
#pragma unroll
        for (int ct = 0; ct < 4; ct++)
#pragma unroll
            for (int rg = 0; rg < 4; rg++) {
                int r_loc = w * 32 + rt * 16 + lh * 4 + rg;
                int c = ct * 16 + lr;
                vals[r_loc][c] = 1.f / (1.f + __expf(-acc[rt][ct][rg]));
            }
    __syncthreads();

    float acc_s = 0.f;
    int cur = ob[0];
#pragma unroll
    for (int rr = 0; rr < 32; rr++) {
        float v = vals[w * 32 + rr][lane] * sv[rr];
        if (ob[rr] != cur) {
            int s = off[cur], e = off[cur + 1];
            if (s >= base_w && e <= base_w + 32)
                st_out[(size_t)cur * B + lane] = acc_s;
            else
                atomicAdd(&st_out[(size_t)cur * B + lane], acc_s);
            acc_s = 0.f;
            cur = ob[rr];
        }
        acc_s += v;
    }
    {
        int s = off[cur], e = off[cur + 1];
        if (s >= base_w && e <= base_w + 32)
            st_out[(size_t)cur * B + lane] = acc_s;
        else
            atomicAdd(&st_out[(size_t)cur * B + lane], acc_s);
    }
}

// ---------- final transpose ----------
__global__ __launch_bounds__(256) void k_out(const float* __restrict__ ST,
                                             float* __restrict__ out) {
    __shared__ float tile[64][65];
    int t = blockIdx.x >> 5;
    int s0 = (blockIdx.x & 31) * 64;
    const float* src = ST + (size_t)(t + 1) * SIZE * B;
    int tid = threadIdx.x;
    for (int i = tid; i < 64 * 64; i += 256) {
        int si = i >> 6, b = i & 63;
        tile[si][b] = src[(size_t)(s0 + si) * B + b];
    }
    __syncthreads();
    for (int i = tid; i < 64 * 64; i += 256) {
        int b = i >> 6, si = i & 63;
        out[((size_t)b * L + t) * SIZE + s0 + si] = tile[si][b];
    }
}

extern "C" void kernel_launch(void* const* d_in, const int* in_sizes, int n_in,
                              void* d_out, int out_size, void* d_ws,
                              size_t ws_size, hipStream_t stream) {
    const int* x = (const int*)d_in[0];
    const int* rel_subj = (const int*)d_in[1];
    const int* rel_obj = (const int*)d_in[2];
    const float* action_emb = (const float*)d_in[3];
    const float* pos_emb = (const float*)d_in[4];
    const float* state_emb = (const float*)d_in[5];
    const float* s2r_w1 = (const float*)d_in[6];
    const float* s2r_b1 = (const float*)d_in[7];
    const float* s2r_w2 = (const float*)d_in[8];
    const float* s2r_b2 = (const float*)d_in[9];
    const float* q_w = (const float*)d_in[10];
    const float* q_b = (const float*)d_in[11];
    const float* ms_w1 = (const float*)d_in[12];
    const float* ms_b1 = (const float*)d_in[13];
    const float* ms_w2 = (const float*)d_in[14];
    const float* ms_b2 = (const float*)d_in[15];
    const float* meta_init = (const float*)d_in[16];

    float* ws = (float*)d_ws;
    float* ST = ws;
    unsigned short* relS = (unsigned short*)(ws + ST_ELEMS);
    unsigned short* metas_bf = relS + (size_t)R_N * 64;
    float* P1 = (float*)(metas_bf + (size_t)L * B * A);
    float* P2 = P1 + SIZE * HID;
    int* ibase = (int*)(P2 + SIZE * HID);
    int* hist = ibase;
    int* off = ibase + 2048;
    int* cursor = off + 2049;
    int* subjS = cursor + 2048;
    int* objS = subjS + R_N;
    // w2t scratch lives in d_out's first 32 KB; k_out fully overwrites later.
    unsigned short* w2t = (unsigned short*)d_out;
    float* out = (float*)d_out;

    k_init<<<256, 256, 0, stream>>>(x, ST, hist, cursor);
    k_hist<<<64, 256, 0, stream>>>(rel_obj, hist);
    k_scan<<<2, 256, 0, stream>>>(hist, off, s2r_w2, w2t);
    k_scatter<<<64, 256, 0, stream>>>(rel_subj, rel_obj, off, cursor, subjS, objS);
    k_p12<<<SIZE / 8, 256, 0, stream>>>(state_emb, s2r_w1, P1, P2);
    k_rel2<<<R_N / RPB, 256, 0, stream>>>(subjS, objS, P1, P2, s2r_b1, w2t,
                                          s2r_b2, relS);
    k_meta<<<B, 1024, 0, stream>>>(x, action_emb, pos_emb, q_w, q_b, ms_w1,
                                   ms_b1, ms_w2, ms_b2, meta_init, metas_bf);
    for (int t = 0; t < L; t++) {
        k_step<<<R_N / RPB, 256, 0, stream>>>(
            off, subjS, objS, relS, metas_bf + (size_t)t * B * A,
            ST + (size_t)t * SIZE * B, ST + (size_t)(t + 1) * SIZE * B);
    }
    k_out<<<512, 256, 0, stream>>>(ST, out);
}